// Round 1
// baseline (163.983 us; speedup 1.0000x reference)
//
#include <hip/hip_runtime.h>
#include <math.h>

#define B_      16
#define K_      200000
#define N_      40
#define TPB     256
#define PAIRS   4                              // pairs of elements per thread
#define TILE    (TPB * PAIRS * 2)              // 2048 elements per block
#define NBX     ((K_ + TILE - 1) / TILE)       // 98
#define NBLOCKS (NBX * B_)                     // 1568
#define NE      (2 * N_)                       // 80 endpoints
#define NACC    7

// ws layout:
//   [0, PART_BYTES)            : per-block partials (NBLOCKS x 7 floats)
//   [TBL_OFF + b*TBL_STRIDE..) : per-batch tables:
//       float  bp[80]   @ +0     sorted endpoints
//       float4 at4[80]  @ +320   (tl,tr,lab,valid) winner when c == bp[i]
//       float4 gap4[81] @ +1600  (tl,tr,lab,valid) winner for open gap (bp[i-1],bp[i])
#define PART_BYTES  (NBLOCKS * NACC * 4)       // 43,904
#define TBL_OFF     PART_BYTES
#define TBL_STRIDE  3072                       // total ws: 43,904 + 49,152 = 93,056 B

__global__ __launch_bounds__(256) void msl_setup(
    const float* __restrict__ targets, char* __restrict__ ws)
{
    __shared__ float tl0[N_], tr0[N_], lb0[N_], ar0[N_];
    __shared__ float stl[N_], str[N_], slb[N_];
    __shared__ float ep[NE], bp[NE];
    const int b = blockIdx.x, t = threadIdx.x;

    if (t < N_) {
        const float* tg = targets + (b * N_ + t) * 3;
        const float tl = tg[0], tr = tg[1];
        tl0[t] = tl; tr0[t] = tr; lb0[t] = tg[2];
        ar0[t] = (tr - tl) * 256.0f;
    }
    __syncthreads();

    // stable rank-sort segments by area (tie: original index) -> priority order
    if (t < N_) {
        const float an = ar0[t];
        int r = 0;
        #pragma unroll
        for (int m = 0; m < N_; ++m) {
            const float am = ar0[m];
            r += (am < an) || (am == an && m < t);
        }
        stl[r] = tl0[t]; str[r] = tr0[t]; slb[r] = lb0[t];
    }
    if (t < NE) ep[t] = (t < N_) ? tl0[t] : tr0[t - N_];
    __syncthreads();

    // rank-sort endpoints
    if (t < NE) {
        const float v = ep[t];
        int r = 0;
        #pragma unroll
        for (int m = 0; m < NE; ++m) {
            const float vm = ep[m];
            r += (vm < v) || (vm == v && m < t);
        }
        bp[r] = v;
    }
    __syncthreads();

    char* tb = ws + TBL_OFF + b * TBL_STRIDE;

    // point winners: first (priority-order) segment with stl<=v<=str
    if (t < NE) {
        const float v = bp[t];
        int w = N_;
        for (int s = N_ - 1; s >= 0; --s)
            w = (stl[s] <= v && v <= str[s]) ? s : w;
        const bool ok = (w < N_);
        const int si = ok ? w : 0;
        ((float4*)(tb + 320))[t] = ok
            ? make_float4(stl[si], str[si], slb[si], 1.0f)
            : make_float4(0.f, 0.f, 0.f, 0.f);
        ((float*)tb)[t] = v;
    }
    // gap winners: open interval (a, bb) entirely inside [stl, str]
    if (t >= 128 && t < 128 + NE + 1) {
        const int g = t - 128;                 // 0..80
        const float a  = g ? bp[g - 1] : -INFINITY;
        const float bb = (g < NE) ? bp[g] : INFINITY;
        int w = N_;
        for (int s = N_ - 1; s >= 0; --s)
            w = (stl[s] <= a && bb <= str[s]) ? s : w;
        const bool ok = (w < N_);
        const int si = ok ? w : 0;
        ((float4*)(tb + 1600))[g] = ok
            ? make_float4(stl[si], str[si], slb[si], 1.0f)
            : make_float4(0.f, 0.f, 0.f, 0.f);
    }
}

__device__ __forceinline__ void elem_accum(
    const float c, const float pl, const float pr,
    const float x0, const float x1,
    const float p0, const float p1,
    const float y0, const float y1,
    const float lg,
    const int base, const int end,
    const float* __restrict__ s_bp,
    const float4* __restrict__ s_at,
    const float4* __restrict__ s_gap,
    float& f0, float& f1, float& f2, float& f3,
    float& f4, float& f5, float& f6)
{
    const float EPS = 1.1920928955078125e-7f;  // FLT_EPSILON

    // ---- match: pos = #bp <= c; in-range bp are contiguous [base,end) ----
    int pos = base; bool eq = false;
    for (int i = base; i < end; ++i) {           // block-uniform bounds
        const float v = s_bp[i];                 // broadcast read
        pos += (v <= c) ? 1 : 0;
        eq  |= (v == c);
    }
    const float4 sg = eq ? s_at[pos - 1] : s_gap[pos];

    const float tl = sg.x, tr = sg.y;
    const int conf_t = (int)sg.z;                // 0 when unmatched
    const float lt0 = (c - tl) * 256.0f;
    const float lt1 = (tr - c) * 256.0f;

    // ---- iou(loc, loc_t) ----
    const float inter = fminf(pl, lt0) + fminf(pr, lt1);
    const float uni   = pl + pr + (lt0 + lt1) - inter;
    const float iou   = __fdividef(inter, fmaxf(uni, EPS));
    const int pconf_t = (iou < 0.5f) ? 0 : conf_t;

    const float posf = (conf_t > 0) ? 1.0f : 0.0f;
    const float ppf  = (pconf_t > 0) ? 1.0f : 0.0f;

    // GIoU (pos only)
    const float ac   = fmaxf(pl, lt0) + fmaxf(pr, lt1);
    const float giou = iou - __fdividef(ac - uni, fmaxf(ac, EPS));
    f0 += (1.0f - giou) * posf;

    // prop loc L1 (prop-pos only)
    const float prop_w = pl + pr;
    const float rw = __fdividef(1.0f, 0.5f * prop_w);
    const float plt0 = (lt0 - pl) * rw;
    const float plt1 = (lt1 - pr) * rw;
    f2 += (fabsf(p0 - plt0) + fabsf(p1 - plt1)) * ppf;

    // centerness BCE (pos only)
    const float cur0 = 0.5f * prop_w * p0 + pl;
    const float cur1 = 0.5f * prop_w * p1 + pr;
    const float inter2 = fminf(cur0, lt0) + fminf(cur1, lt1);
    const float uni2   = cur0 + cur1 + (lt0 + lt1) - inter2;
    const float iou2   = fmaxf(__fdividef(inter2, fmaxf(uni2, EPS)), 0.0f);
    const float bce = fmaxf(lg, 0.0f) - lg * iou2
                      + __logf(1.0f + __expf(-fabsf(lg)));
    f4 += bce * posf;

    // focal on conf (all elements)
    {
        const float xt = conf_t ? x1 : x0;
        const float xo = conf_t ? x0 : x1;
        const float pt = __fdividef(1.0f, 1.0f + __expf(xo - xt)) + 1e-6f;
        const float al = conf_t ? 0.75f : 0.25f;
        const float om = 1.0f - pt;
        f1 += -om * om * al * __logf(pt);
    }
    // focal on prop_conf (all elements)
    {
        const float xt = pconf_t ? y1 : y0;
        const float xo = pconf_t ? y0 : y1;
        const float pt = __fdividef(1.0f, 1.0f + __expf(xo - xt)) + 1e-6f;
        const float al = pconf_t ? 0.75f : 0.25f;
        const float om = 1.0f - pt;
        f3 += -om * om * al * __logf(pt);
    }

    f5 += posf;
    f6 += ppf;
}

__device__ __forceinline__ void do_pair(
    const float* __restrict__ loc,   const float* __restrict__ conf,
    const float* __restrict__ ploc,  const float* __restrict__ pconf,
    const float* __restrict__ center, const float* __restrict__ priors,
    const int bK, const int k,
    const int base, const int end,
    const float* __restrict__ s_bp,
    const float4* __restrict__ s_at,
    const float4* __restrict__ s_gap,
    float& f0, float& f1, float& f2, float& f3,
    float& f4, float& f5, float& f6)
{
    // k is even; two adjacent elements (k, k+1) -> one float4 per (B,K,2) array
    const int i4 = (bK + k) >> 1;                 // float4 index into (B,K,2)
    const float4 l4 = ((const float4*)loc)[i4];
    const float4 c4 = ((const float4*)conf)[i4];
    const float4 p4 = ((const float4*)ploc)[i4];
    const float4 q4 = ((const float4*)pconf)[i4];
    const float2 g2 = *(const float2*)(center + bK + k);
    const float2 r2 = *(const float2*)(priors + k);

    elem_accum(r2.x, l4.x, l4.y, c4.x, c4.y, p4.x, p4.y, q4.x, q4.y, g2.x,
               base, end, s_bp, s_at, s_gap, f0, f1, f2, f3, f4, f5, f6);
    elem_accum(r2.y, l4.z, l4.w, c4.z, c4.w, p4.z, p4.w, q4.z, q4.w, g2.y,
               base, end, s_bp, s_at, s_gap, f0, f1, f2, f3, f4, f5, f6);
}

__global__ __launch_bounds__(TPB) void msl_main(
    const float* __restrict__ loc,     // (B,K,2)
    const float* __restrict__ conf,    // (B,K,2)
    const float* __restrict__ ploc,    // (B,K,2)
    const float* __restrict__ pconf,   // (B,K,2)
    const float* __restrict__ center,  // (B,K,1)
    const float* __restrict__ priors,  // (K,1)
    char* __restrict__ ws)
{
    __shared__ float  s_bp[NE];
    __shared__ float4 s_at[NE];
    __shared__ float4 s_gap[NE + 1];
    __shared__ int    s_cnt[4];        // {base_w0, base_w1, end_w0, end_w1}
    __shared__ double s_red[TPB / 64][NACC];

    const int b = blockIdx.y;
    const int t = threadIdx.x;
    const int kb = blockIdx.x * TILE;
    const int kend = (kb + TILE < K_) ? kb + TILE : K_;

    // ---- single-phase prologue: table loads + ballot counts, ONE barrier ----
    {
        const char* tb = ws + TBL_OFF + b * TBL_STRIDE;
        // waves 0-1 (t<128): load bp (pad >=80 with +INF), ballot vs block range
        if (t < 128) {
            const float v = (t < NE) ? ((const float*)tb)[t] : INFINITY;
            if (t < NE) s_bp[t] = v;
            const float cmin = priors[kb];          // uniform -> s_load
            const float cmax = priors[kend - 1];
            const unsigned long long mlo = __ballot(v < cmin);
            const unsigned long long mhi = __ballot(v <= cmax);
            const int wv = t >> 6;                   // 0 or 1
            if ((t & 63) == 0) {
                s_cnt[wv]     = __popcll(mlo);
                s_cnt[2 + wv] = __popcll(mhi);
            }
        } else if (t < 208) {                        // 80 at4 loads
            s_at[t - 128] = ((const float4*)(tb + 320))[t - 128];
        } else {                                     // 48 threads: first gap4 loads
            s_gap[t - 208] = ((const float4*)(tb + 1600))[t - 208];
        }
        if (t < 33)                                  // remaining 33 gap4 loads
            s_gap[48 + t] = ((const float4*)(tb + 1600))[48 + t];
    }
    __syncthreads();

    const int base = s_cnt[0] + s_cnt[1];            // #bp <  cmin
    const int end  = s_cnt[2] + s_cnt[3];            // #bp <= cmax

    const int bK = b * K_;

    float f0 = 0.f, f1 = 0.f, f2 = 0.f, f3 = 0.f, f4 = 0.f, f5 = 0.f, f6 = 0.f;

    const int k0 = kb + 2 * t;                       // even
    if (kb + TILE <= K_) {
        // fast path: full tile, no bounds checks -> compiler can hoist/batch
        // all 24 vector loads for MLP
        #pragma unroll
        for (int j = 0; j < PAIRS; ++j) {
            const int k = k0 + j * (2 * TPB);
            do_pair(loc, conf, ploc, pconf, center, priors, bK, k,
                    base, end, s_bp, s_at, s_gap, f0, f1, f2, f3, f4, f5, f6);
        }
    } else {
        // tail block (K_ even => pairs never straddle the boundary)
        #pragma unroll
        for (int j = 0; j < PAIRS; ++j) {
            const int k = k0 + j * (2 * TPB);
            if (k < K_)
                do_pair(loc, conf, ploc, pconf, center, priors, bK, k,
                        base, end, s_bp, s_at, s_gap, f0, f1, f2, f3, f4, f5, f6);
        }
    }

    // ---- block reduction -> per-block partials (no global atomics) ----
    double vals[NACC] = {(double)f0, (double)f1, (double)f2, (double)f3,
                         (double)f4, (double)f5, (double)f6};
    const int wave = t >> 6, lane = t & 63;
    #pragma unroll
    for (int q = 0; q < NACC; ++q) {
        double v = vals[q];
        #pragma unroll
        for (int off = 32; off > 0; off >>= 1)
            v += __shfl_down(v, off, 64);
        if (lane == 0) s_red[wave][q] = v;
    }
    __syncthreads();
    if (t == 0) {
        float* partials = (float*)ws;
        const int bid = blockIdx.y * gridDim.x + blockIdx.x;
        #pragma unroll
        for (int q = 0; q < NACC; ++q) {
            double s = 0.0;
            #pragma unroll
            for (int w2 = 0; w2 < TPB / 64; ++w2) s += s_red[w2][q];
            partials[(long long)bid * NACC + q] = (float)s;
        }
    }
}

__global__ __launch_bounds__(TPB) void msl_final(
    const float* __restrict__ partials, float* __restrict__ out)
{
    __shared__ double s_red[TPB / 64][NACC];
    double acc[NACC] = {0, 0, 0, 0, 0, 0, 0};
    for (int i = threadIdx.x; i < NBLOCKS; i += TPB) {
        #pragma unroll
        for (int q = 0; q < NACC; ++q)
            acc[q] += (double)partials[(long long)i * NACC + q];
    }
    const int wave = threadIdx.x >> 6, lane = threadIdx.x & 63;
    #pragma unroll
    for (int q = 0; q < NACC; ++q) {
        double v = acc[q];
        #pragma unroll
        for (int off = 32; off > 0; off >>= 1)
            v += __shfl_down(v, off, 64);
        if (lane == 0) s_red[wave][q] = v;
    }
    __syncthreads();
    if (threadIdx.x == 0) {
        double s[NACC];
        #pragma unroll
        for (int q = 0; q < NACC; ++q) {
            double v = 0.0;
            #pragma unroll
            for (int w = 0; w < TPB / 64; ++w) v += s_red[w][q];
            s[q] = v;
        }
        const double Np = fmax(s[5], 1.0);
        const double PN = fmax(s[6], 1.0);
        out[0] = (float)(s[0] / Np);
        out[1] = (float)(s[1] / Np);
        out[2] = (float)(s[2] / PN);
        out[3] = (float)(s[3] / PN);
        out[4] = (float)(s[4] / Np);
    }
}

extern "C" void kernel_launch(void* const* d_in, const int* in_sizes, int n_in,
                              void* d_out, int out_size, void* d_ws, size_t ws_size,
                              hipStream_t stream) {
    const float* loc     = (const float*)d_in[0];
    const float* conf    = (const float*)d_in[1];
    const float* ploc    = (const float*)d_in[2];
    const float* pconf   = (const float*)d_in[3];
    const float* center  = (const float*)d_in[4];
    const float* priors  = (const float*)d_in[5];
    const float* targets = (const float*)d_in[6];
    char* ws = (char*)d_ws;   // uses 43,904 + 16*3072 = 93,056 bytes

    msl_setup<<<B_, 256, 0, stream>>>(targets, ws);
    dim3 grid(NBX, B_);
    msl_main<<<grid, TPB, 0, stream>>>(loc, conf, ploc, pconf, center, priors, ws);
    msl_final<<<1, TPB, 0, stream>>>((const float*)ws, (float*)d_out);
}

// Round 2
// 159.184 us; speedup vs baseline: 1.0301x; 1.0301x over previous
//
#include <hip/hip_runtime.h>
#include <math.h>

#define B_      16
#define K_      200000
#define N_      40
#define TPB     256
#define ITEMS   4
#define TILE    (TPB * ITEMS)                 // 1024 elements per block
#define NBX     ((K_ + TILE - 1) / TILE)      // 196
#define NBLOCKS (NBX * B_)                    // 3136
#define NE      (2 * N_)                      // 80 endpoints
#define NACC    7

// ws layout:
//   [0, PART_BYTES)            : per-block partials (NBLOCKS x 7 floats)
//   [TBL_OFF + b*TBL_STRIDE..) : per-batch tables:
//       float  bp[80]   @ +0     sorted endpoints
//       float4 at4[80]  @ +320   (tl,tr,lab,valid) winner when c == bp[i]
//       float4 gap4[81] @ +1600  (tl,tr,lab,valid) winner for open gap (bp[i-1],bp[i])
#define PART_BYTES  (NBLOCKS * NACC * 4)      // 87,808
#define TBL_OFF     PART_BYTES
#define TBL_STRIDE  3072                      // total ws: 87,808 + 49,152 = 136,960 B

__global__ __launch_bounds__(256) void msl_setup(
    const float* __restrict__ targets, char* __restrict__ ws)
{
    __shared__ float tl0[N_], tr0[N_], lb0[N_], ar0[N_];
    __shared__ float stl[N_], str[N_], slb[N_];
    __shared__ float ep[NE], bp[NE];
    const int b = blockIdx.x, t = threadIdx.x;

    if (t < N_) {
        const float* tg = targets + (b * N_ + t) * 3;
        const float tl = tg[0], tr = tg[1];
        tl0[t] = tl; tr0[t] = tr; lb0[t] = tg[2];
        ar0[t] = (tr - tl) * 256.0f;
    }
    __syncthreads();

    // stable rank-sort segments by area (tie: original index) -> priority order
    if (t < N_) {
        const float an = ar0[t];
        int r = 0;
        #pragma unroll
        for (int m = 0; m < N_; ++m) {
            const float am = ar0[m];
            r += (am < an) || (am == an && m < t);
        }
        stl[r] = tl0[t]; str[r] = tr0[t]; slb[r] = lb0[t];
    }
    if (t < NE) ep[t] = (t < N_) ? tl0[t] : tr0[t - N_];
    __syncthreads();

    // rank-sort endpoints
    if (t < NE) {
        const float v = ep[t];
        int r = 0;
        #pragma unroll
        for (int m = 0; m < NE; ++m) {
            const float vm = ep[m];
            r += (vm < v) || (vm == v && m < t);
        }
        bp[r] = v;
    }
    __syncthreads();

    char* tb = ws + TBL_OFF + b * TBL_STRIDE;

    // point winners: first (priority-order) segment with stl<=v<=str
    if (t < NE) {
        const float v = bp[t];
        int w = N_;
        for (int s = N_ - 1; s >= 0; --s)
            w = (stl[s] <= v && v <= str[s]) ? s : w;
        const bool ok = (w < N_);
        const int si = ok ? w : 0;
        ((float4*)(tb + 320))[t] = ok
            ? make_float4(stl[si], str[si], slb[si], 1.0f)
            : make_float4(0.f, 0.f, 0.f, 0.f);
        ((float*)tb)[t] = v;
    }
    // gap winners: open interval (a, bb) entirely inside [stl, str]
    if (t >= 128 && t < 128 + NE + 1) {
        const int g = t - 128;                 // 0..80
        const float a  = g ? bp[g - 1] : -INFINITY;
        const float bb = (g < NE) ? bp[g] : INFINITY;
        int w = N_;
        for (int s = N_ - 1; s >= 0; --s)
            w = (stl[s] <= a && bb <= str[s]) ? s : w;
        const bool ok = (w < N_);
        const int si = ok ? w : 0;
        ((float4*)(tb + 1600))[g] = ok
            ? make_float4(stl[si], str[si], slb[si], 1.0f)
            : make_float4(0.f, 0.f, 0.f, 0.f);
    }
}

__device__ __forceinline__ void elem_accum(
    const float c, const float pl, const float pr,
    const float x0, const float x1,
    const float p0, const float p1,
    const float y0, const float y1,
    const float lg,
    const int base, const int end,
    const float* __restrict__ s_bp,
    const float4* __restrict__ s_at,
    const float4* __restrict__ s_gap,
    float& f0, float& f1, float& f2, float& f3,
    float& f4, float& f5, float& f6)
{
    const float EPS = 1.1920928955078125e-7f;  // FLT_EPSILON

    // ---- match: pos = #bp <= c; in-range bp are contiguous [base,end) ----
    int pos = base; bool eq = false;
    for (int i = base; i < end; ++i) {           // block-uniform bounds
        const float v = s_bp[i];                 // broadcast read
        pos += (v <= c) ? 1 : 0;
        eq  |= (v == c);
    }
    const float4 sg = eq ? s_at[pos - 1] : s_gap[pos];

    const float tl = sg.x, tr = sg.y;
    const int conf_t = (int)sg.z;                // 0 when unmatched
    const float lt0 = (c - tl) * 256.0f;
    const float lt1 = (tr - c) * 256.0f;

    // ---- iou(loc, loc_t) ----
    const float inter = fminf(pl, lt0) + fminf(pr, lt1);
    const float uni   = pl + pr + (lt0 + lt1) - inter;
    const float iou   = __fdividef(inter, fmaxf(uni, EPS));
    const int pconf_t = (iou < 0.5f) ? 0 : conf_t;

    const float posf = (conf_t > 0) ? 1.0f : 0.0f;
    const float ppf  = (pconf_t > 0) ? 1.0f : 0.0f;

    // GIoU (pos only)
    const float ac   = fmaxf(pl, lt0) + fmaxf(pr, lt1);
    const float giou = iou - __fdividef(ac - uni, fmaxf(ac, EPS));
    f0 += (1.0f - giou) * posf;

    // prop loc L1 (prop-pos only)
    const float prop_w = pl + pr;
    const float rw = __fdividef(1.0f, 0.5f * prop_w);
    const float plt0 = (lt0 - pl) * rw;
    const float plt1 = (lt1 - pr) * rw;
    f2 += (fabsf(p0 - plt0) + fabsf(p1 - plt1)) * ppf;

    // centerness BCE (pos only)
    const float cur0 = 0.5f * prop_w * p0 + pl;
    const float cur1 = 0.5f * prop_w * p1 + pr;
    const float inter2 = fminf(cur0, lt0) + fminf(cur1, lt1);
    const float uni2   = cur0 + cur1 + (lt0 + lt1) - inter2;
    const float iou2   = fmaxf(__fdividef(inter2, fmaxf(uni2, EPS)), 0.0f);
    const float bce = fmaxf(lg, 0.0f) - lg * iou2
                      + __logf(1.0f + __expf(-fabsf(lg)));
    f4 += bce * posf;

    // focal on conf (all elements)
    {
        const float xt = conf_t ? x1 : x0;
        const float xo = conf_t ? x0 : x1;
        const float pt = __fdividef(1.0f, 1.0f + __expf(xo - xt)) + 1e-6f;
        const float al = conf_t ? 0.75f : 0.25f;
        const float om = 1.0f - pt;
        f1 += -om * om * al * __logf(pt);
    }
    // focal on prop_conf (all elements)
    {
        const float xt = pconf_t ? y1 : y0;
        const float xo = pconf_t ? y0 : y1;
        const float pt = __fdividef(1.0f, 1.0f + __expf(xo - xt)) + 1e-6f;
        const float al = pconf_t ? 0.75f : 0.25f;
        const float om = 1.0f - pt;
        f3 += -om * om * al * __logf(pt);
    }

    f5 += posf;
    f6 += ppf;
}

__global__ __launch_bounds__(TPB) void msl_main(
    const float* __restrict__ loc,     // (B,K,2)
    const float* __restrict__ conf,    // (B,K,2)
    const float* __restrict__ ploc,    // (B,K,2)
    const float* __restrict__ pconf,   // (B,K,2)
    const float* __restrict__ center,  // (B,K,1)
    const float* __restrict__ priors,  // (K,1)
    char* __restrict__ ws)
{
    __shared__ float  s_bp[NE];
    __shared__ float4 s_at[NE];
    __shared__ float4 s_gap[NE + 1];
    __shared__ int    s_cnt[4];        // {base_w0, base_w1, end_w0, end_w1}
    __shared__ double s_red[TPB / 64][NACC];

    const int b = blockIdx.y;
    const int t = threadIdx.x;
    const int kb = blockIdx.x * TILE;
    const int kend = (kb + TILE < K_) ? kb + TILE : K_;

    // ---- single-phase prologue: table loads + ballot counts, ONE barrier ----
    {
        const char* tb = ws + TBL_OFF + b * TBL_STRIDE;
        // waves 0-1 (t<128): load bp (pad >=80 with +INF), ballot vs block range
        if (t < 128) {
            const float v = (t < NE) ? ((const float*)tb)[t] : INFINITY;
            if (t < NE) s_bp[t] = v;
            const float cmin = priors[kb];          // uniform -> s_load
            const float cmax = priors[kend - 1];
            const unsigned long long mlo = __ballot(v < cmin);
            const unsigned long long mhi = __ballot(v <= cmax);
            const int wv = t >> 6;                   // 0 or 1
            if ((t & 63) == 0) {
                s_cnt[wv]     = __popcll(mlo);
                s_cnt[2 + wv] = __popcll(mhi);
            }
        } else if (t < 208) {                        // 80 at4 loads
            s_at[t - 128] = ((const float4*)(tb + 320))[t - 128];
        } else {                                     // 48 threads: first gap4 loads
            s_gap[t - 208] = ((const float4*)(tb + 1600))[t - 208];
        }
        if (t < 33)                                  // remaining 33 gap4 loads
            s_gap[48 + t] = ((const float4*)(tb + 1600))[48 + t];
    }
    __syncthreads();

    const int base = s_cnt[0] + s_cnt[1];            // #bp <  cmin
    const int end  = s_cnt[2] + s_cnt[3];            // #bp <= cmax

    const int bK  = b * K_;
    const int bK2 = bK * 2;

    float f0 = 0.f, f1 = 0.f, f2 = 0.f, f3 = 0.f, f4 = 0.f, f5 = 0.f, f6 = 0.f;

    const int kbase = kb + t;
    if (kb + TILE <= K_) {
        // ---- fast path (195/196 blocks): explicit prefetch of ALL loads ----
        // 24 independent global loads in flight before any compute consumes
        // one -> converts serial dependency chains into MLP. Registers are
        // statically indexed (full unroll) so nothing spills to scratch.
        float2 l2[ITEMS], cf2[ITEMS], pl2[ITEMS], pc2[ITEMS];
        float  lg[ITEMS], cc[ITEMS];
        #pragma unroll
        for (int j = 0; j < ITEMS; ++j) {
            const int k  = kbase + j * TPB;
            const int i2 = bK2 + k * 2;
            l2[j]  = *(const float2*)(loc   + i2);
            cf2[j] = *(const float2*)(conf  + i2);
            pl2[j] = *(const float2*)(ploc  + i2);
            pc2[j] = *(const float2*)(pconf + i2);
            lg[j]  = center[bK + k];
            cc[j]  = priors[k];
        }
        __builtin_amdgcn_sched_barrier(0);  // keep loads batched above compute
        #pragma unroll
        for (int j = 0; j < ITEMS; ++j) {
            elem_accum(cc[j], l2[j].x, l2[j].y, cf2[j].x, cf2[j].y,
                       pl2[j].x, pl2[j].y, pc2[j].x, pc2[j].y, lg[j],
                       base, end, s_bp, s_at, s_gap,
                       f0, f1, f2, f3, f4, f5, f6);
        }
    } else {
        // ---- tail blocks (16/3136): original bounds-checked loop ----
        #pragma unroll
        for (int j = 0; j < ITEMS; ++j) {
            const int k = kbase + j * TPB;
            if (k >= K_) continue;
            const int i2 = bK2 + k * 2;
            const float2 l2  = *(const float2*)(loc   + i2);
            const float2 cf2 = *(const float2*)(conf  + i2);
            const float2 pl2 = *(const float2*)(ploc  + i2);
            const float2 pc2 = *(const float2*)(pconf + i2);
            elem_accum(priors[k], l2.x, l2.y, cf2.x, cf2.y,
                       pl2.x, pl2.y, pc2.x, pc2.y, center[bK + k],
                       base, end, s_bp, s_at, s_gap,
                       f0, f1, f2, f3, f4, f5, f6);
        }
    }

    // ---- block reduction -> per-block partials (no global atomics) ----
    double vals[NACC] = {(double)f0, (double)f1, (double)f2, (double)f3,
                         (double)f4, (double)f5, (double)f6};
    const int wave = t >> 6, lane = t & 63;
    #pragma unroll
    for (int q = 0; q < NACC; ++q) {
        double v = vals[q];
        #pragma unroll
        for (int off = 32; off > 0; off >>= 1)
            v += __shfl_down(v, off, 64);
        if (lane == 0) s_red[wave][q] = v;
    }
    __syncthreads();
    if (t == 0) {
        float* partials = (float*)ws;
        const int bid = blockIdx.y * gridDim.x + blockIdx.x;
        #pragma unroll
        for (int q = 0; q < NACC; ++q) {
            double s = 0.0;
            #pragma unroll
            for (int w2 = 0; w2 < TPB / 64; ++w2) s += s_red[w2][q];
            partials[(long long)bid * NACC + q] = (float)s;
        }
    }
}

__global__ __launch_bounds__(TPB) void msl_final(
    const float* __restrict__ partials, float* __restrict__ out)
{
    __shared__ double s_red[TPB / 64][NACC];
    double acc[NACC] = {0, 0, 0, 0, 0, 0, 0};
    for (int i = threadIdx.x; i < NBLOCKS; i += TPB) {
        #pragma unroll
        for (int q = 0; q < NACC; ++q)
            acc[q] += (double)partials[(long long)i * NACC + q];
    }
    const int wave = threadIdx.x >> 6, lane = threadIdx.x & 63;
    #pragma unroll
    for (int q = 0; q < NACC; ++q) {
        double v = acc[q];
        #pragma unroll
        for (int off = 32; off > 0; off >>= 1)
            v += __shfl_down(v, off, 64);
        if (lane == 0) s_red[wave][q] = v;
    }
    __syncthreads();
    if (threadIdx.x == 0) {
        double s[NACC];
        #pragma unroll
        for (int q = 0; q < NACC; ++q) {
            double v = 0.0;
            #pragma unroll
            for (int w = 0; w < TPB / 64; ++w) v += s_red[w][q];
            s[q] = v;
        }
        const double Np = fmax(s[5], 1.0);
        const double PN = fmax(s[6], 1.0);
        out[0] = (float)(s[0] / Np);
        out[1] = (float)(s[1] / Np);
        out[2] = (float)(s[2] / PN);
        out[3] = (float)(s[3] / PN);
        out[4] = (float)(s[4] / Np);
    }
}

extern "C" void kernel_launch(void* const* d_in, const int* in_sizes, int n_in,
                              void* d_out, int out_size, void* d_ws, size_t ws_size,
                              hipStream_t stream) {
    const float* loc     = (const float*)d_in[0];
    const float* conf    = (const float*)d_in[1];
    const float* ploc    = (const float*)d_in[2];
    const float* pconf   = (const float*)d_in[3];
    const float* center  = (const float*)d_in[4];
    const float* priors  = (const float*)d_in[5];
    const float* targets = (const float*)d_in[6];
    char* ws = (char*)d_ws;   // uses 87,808 + 16*3072 = 136,960 bytes

    msl_setup<<<B_, 256, 0, stream>>>(targets, ws);
    dim3 grid(NBX, B_);
    msl_main<<<grid, TPB, 0, stream>>>(loc, conf, ploc, pconf, center, priors, ws);
    msl_final<<<1, TPB, 0, stream>>>((const float*)ws, (float*)d_out);
}